// Round 6
// baseline (466.879 us; speedup 1.0000x reference)
//
#include <hip/hip_runtime.h>
#include <hip/hip_bf16.h>
#include <stdint.h>

#define NROW 8192
#define NCOL 8192
#define INF 256
#define OUTF 256

typedef __attribute__((ext_vector_type(4))) float f32x4;
typedef __attribute__((ext_vector_type(8))) short s16x8;
typedef __attribute__((ext_vector_type(4))) int i32x4;
typedef __attribute__((ext_vector_type(2))) unsigned int u32x2;

__device__ __forceinline__ short f2bf(float f) {
  unsigned int u = __builtin_bit_cast(unsigned int, f);
  unsigned int r = (u + 0x7FFFu + ((u >> 16) & 1u)) >> 16;  // RTNE
  return (short)r;
}
__device__ __forceinline__ float bf2f(short s) {
  unsigned int u = ((unsigned int)(unsigned short)s) << 16;
  return __builtin_bit_cast(float, u);
}
__device__ __forceinline__ unsigned int pkbf(float lo, float hi) {
#if __has_builtin(__builtin_amdgcn_cvt_pk_bf16_f32)
  auto t = __builtin_amdgcn_cvt_pk_bf16_f32(lo, hi);
  return __builtin_bit_cast(unsigned int, t);
#else
  unsigned int r;
  asm("v_cvt_pk_bf16_f32 %0, %1, %2" : "=v"(r) : "v"(lo), "v"(hi));
  return r;
#endif
}

#define GLDS(g, l)                                                            \
  __builtin_amdgcn_global_load_lds(                                           \
      (const __attribute__((address_space(1))) void*)(g),                     \
      (__attribute__((address_space(3))) void*)(l), 16, 0, 0)

// ---------------------------------------------------------------------------
// K1: dis[i] = 1/sqrt(1 + sum_j A[i,j])  AND  Abf = bf16(A) row-major.
// One wave per row, 4 rows/block. Sum in fp32 (accuracy); write bf16 copy
// so k_gemm streams half the bytes (and skips in-loop cvt entirely).
// ---------------------------------------------------------------------------
__global__ __launch_bounds__(256) void k_deg(const float* __restrict__ A,
                                             float* __restrict__ dis,
                                             short* __restrict__ Abf) {
  const int wave = threadIdx.x >> 6, lane = threadIdx.x & 63;
  const int row = (blockIdx.x << 2) + wave;
  const f32x4* Ar = (const f32x4*)(A + (size_t)row * NCOL);
  u32x2* Br = (u32x2*)(Abf + (size_t)row * NCOL);
  float s = 0.f;
#pragma unroll 4
  for (int it = 0; it < 32; ++it) {
    f32x4 v = Ar[(it << 6) + lane];
    s += (v.x + v.y) + (v.z + v.w);
    u32x2 p;
    p.x = pkbf(v.x, v.y);
    p.y = pkbf(v.z, v.w);
    Br[(it << 6) + lane] = p;
  }
#pragma unroll
  for (int off = 32; off > 0; off >>= 1) s += __shfl_down(s, off, 64);
  if (lane == 0) dis[row] = 1.0f / sqrtf(s + 1.0f);
}

// ---------------------------------------------------------------------------
// K2: Ytf = bf16(X^T * d) in MFMA-B FRAGMENT ORDER:
//   frag (ftile=f>>4, kb=j>>5) is 512 contiguous shorts;
//   pos = lane*8 + elem, lane = (f&15) + 16*((j&31)>>3), elem = j&7.
// Yrm[j][f] = bf16(X[j][f]*d[j]) row-major (+I term).
// Wbf = bf16(W) in the same fragment order over (out_f, in_f).
// ---------------------------------------------------------------------------
__global__ __launch_bounds__(256) void k_prep(const float* __restrict__ X,
                                              const float* __restrict__ W,
                                              const float* __restrict__ dis,
                                              short* __restrict__ Ytf,
                                              short* __restrict__ Yrm,
                                              short* __restrict__ Wbf) {
  __shared__ short T[256][72];  // [f][j-local], 144B rows (16B aligned)
  __shared__ float sd[64];
  const int tid = threadIdx.x;

  if (blockIdx.x >= 128) {  // W convert, frag-ordered
    const int idx8 = (((int)blockIdx.x - 128) * 256 + tid) << 3;
    const int o = idx8 >> 8, k = idx8 & 255;  // 8 consecutive k, k%8==0
    f32x4 a = *(const f32x4*)(W + idx8);
    f32x4 b = *(const f32x4*)(W + idx8 + 4);
    i32x4 v;
    v.x = (int)pkbf(a.x, a.y); v.y = (int)pkbf(a.z, a.w);
    v.z = (int)pkbf(b.x, b.y); v.w = (int)pkbf(b.z, b.w);
    // frag = (o>>4)*8 + (k>>5); lane = (o&15) + 16*((k&31)>>3); elem = 0
    const int dst = (((o >> 4) << 3) + (k >> 5)) * 512 +
                    ((o & 15) << 3) + (((k & 31) >> 3) << 7);
    *(i32x4*)(Wbf + dst) = v;
    return;
  }

  const int jb = blockIdx.x << 6;
  if (tid < 64) sd[tid] = dis[jb + tid];
  __syncthreads();
#pragma unroll
  for (int i = 0; i < 16; ++i) {
    const int flat = (i << 8) + tid;
    const int j = flat >> 6;
    const int fc = flat & 63;
    f32x4 v = *(const f32x4*)(X + (size_t)(jb + j) * INF + (fc << 2));
    const float d = sd[j];
    short b0 = f2bf(v.x * d), b1 = f2bf(v.y * d);
    short b2 = f2bf(v.z * d), b3 = f2bf(v.w * d);
    T[(fc << 2) + 0][j] = b0;
    T[(fc << 2) + 1][j] = b1;
    T[(fc << 2) + 2][j] = b2;
    T[(fc << 2) + 3][j] = b3;
    u32x2 p;
    p.x = (unsigned int)(unsigned short)b0 | ((unsigned int)(unsigned short)b1 << 16);
    p.y = (unsigned int)(unsigned short)b2 | ((unsigned int)(unsigned short)b3 << 16);
    *(u32x2*)(Yrm + (size_t)(jb + j) * INF + (fc << 2)) = p;
  }
  __syncthreads();
  const int f = tid;
#pragma unroll
  for (int c = 0; c < 8; ++c) {
    s16x8 v = *(const s16x8*)&T[f][c << 3];
    const int j = jb + (c << 3);
    const size_t dst = ((size_t)(((f >> 4) << 8) + (j >> 5)) << 9) +
                       (((f & 15) + (((j & 31) >> 3) << 4)) << 3);
    *(s16x8*)(Ytf + dst) = v;
  }
}

// ---------------------------------------------------------------------------
// K3: P[sp] = Abf[128 rows, ksp] @ Yt^T  (bf16 MFMA, fp32 acc)
// BM=128 BN=256 BK=64, 512 thr (8 waves: rw row-half, cw col-strip).
// A: bf16 via GLDS into 2-buffer XOR-swizzled LDS (2x16KB) — no in-loop cvt.
// B: coalesced frag-ordered loads from L2/L3-resident Ytf.
// ---------------------------------------------------------------------------
__global__ __launch_bounds__(512, 4) void k_gemm(const short* __restrict__ Abf,
                                                 const short* __restrict__ Ytf,
                                                 float* __restrict__ P,
                                                 int splits) {
  __shared__ short Ab[2 * 8192];  // 2 x (128 rows x 64 bf16), chunk-swizzled
  const int tid = threadIdx.x;
  const int w = tid >> 6, l = tid & 63, lr = l & 15, lq = l >> 4;
  const int cw = w & 3, rw = w >> 2;
  const int row0 = (int)blockIdx.x << 7;
  const int sp = blockIdx.y;
  const int kspan = NCOL / splits;
  const int k0 = sp * kspan;
  const int steps = kspan >> 6;
  const int mbase = rw << 6;

  // DMA sources: chunk p = tid + j*512 (j=0..1); n=p>>3 (row 0..127),
  // cpos=p&7; global 16B chunk c = cpos ^ (n&7)  (XOR swizzle)
  const short* gA[2];
#pragma unroll
  for (int j = 0; j < 2; ++j) {
    const int p = tid + (j << 9);
    const int n = p >> 3, cpos = p & 7;
    const int c = cpos ^ (n & 7);
    gA[j] = Abf + (size_t)(row0 + n) * NCOL + k0 + (c << 3);
  }
  char* ldst0 = (char*)Ab + ((tid & ~63) << 4);  // wave base (+ lane*16 by HW)

  // frag-ordered B: frag (ftile = cw*4+ct, kb) at Ytf[(ftile*256+kb)*512+l*8]
  const short* Bw = Ytf + ((size_t)cw << 19) + ((size_t)(k0 >> 5) << 9) + (l << 3);

  f32x4 acc[4][4];
#pragma unroll
  for (int rt = 0; rt < 4; ++rt)
#pragma unroll
    for (int ct = 0; ct < 4; ++ct) acc[rt][ct] = (f32x4){0.f, 0.f, 0.f, 0.f};

  // prologue: DMA(0); B(0, kc=0)
  GLDS(gA[0], ldst0);
  GLDS(gA[1], ldst0 + 8192);
  i32x4 bB0[4];
#pragma unroll
  for (int ct = 0; ct < 4; ++ct)
    bB0[ct] = *(const i32x4*)(Bw + ((size_t)ct << 17));

  for (int s = 0; s < steps; ++s) {
    __syncthreads();  // drains DMA(s) + B-prefetches for step s

    if (s + 1 < steps) {
      char* dst = ldst0 + (((s + 1) & 1) << 14);
      const size_t go = (size_t)(s + 1) << 6;  // 64 shorts = 128 B
      GLDS(gA[0] + go, dst);
      GLDS(gA[1] + go, dst + 8192);
    }

    // B(s, kc=1), coalesced, issued early (covered by kc=0 compute)
    i32x4 bB1[4];
#pragma unroll
    for (int ct = 0; ct < 4; ++ct)
      bB1[ct] = *(const i32x4*)(Bw + ((size_t)ct << 17) +
                                ((size_t)((s << 1) + 1) << 9));

    const short* buf = Ab + ((s & 1) << 13);

    // ---- kc = 0: A-frags are direct ds_read_b128 (swizzled) ----
    s16x8 af[4];
#pragma unroll
    for (int rt = 0; rt < 4; ++rt) {
      const int m = mbase + (rt << 4) + lr;
      af[rt] = *(const s16x8*)(buf + (m << 6) + ((lq ^ (m & 7)) << 3));
    }
#pragma unroll
    for (int rt = 0; rt < 4; ++rt) {
      const s16x8 a = af[rt];
#pragma unroll
      for (int ct = 0; ct < 4; ++ct)
        acc[rt][ct] = __builtin_amdgcn_mfma_f32_16x16x32_bf16(
            a, __builtin_bit_cast(s16x8, bB0[ct]), acc[rt][ct], 0, 0, 0);
    }

    if (s + 1 < steps) {  // prefetch B(s+1, kc=0)
#pragma unroll
      for (int ct = 0; ct < 4; ++ct)
        bB0[ct] = *(const i32x4*)(Bw + ((size_t)ct << 17) +
                                  ((size_t)((s << 1) + 2) << 9));
    }

    // ---- kc = 1 ----
#pragma unroll
    for (int rt = 0; rt < 4; ++rt) {
      const int m = mbase + (rt << 4) + lr;
      af[rt] = *(const s16x8*)(buf + (m << 6) + (((4 + lq) ^ (m & 7)) << 3));
    }
#pragma unroll
    for (int rt = 0; rt < 4; ++rt) {
      const s16x8 a = af[rt];
#pragma unroll
      for (int ct = 0; ct < 4; ++ct)
        acc[rt][ct] = __builtin_amdgcn_mfma_f32_16x16x32_bf16(
            a, __builtin_bit_cast(s16x8, bB1[ct]), acc[rt][ct], 0, 0, 0);
    }
  }

  float* Pp = P + ((size_t)sp << 21);
#pragma unroll
  for (int rt = 0; rt < 4; ++rt)
#pragma unroll
    for (int ct = 0; ct < 4; ++ct) {
      const int col = (cw << 6) + (ct << 4) + lr;
      const int row = row0 + (rw << 6) + (rt << 4) + (lq << 2);
#pragma unroll
      for (int r = 0; r < 4; ++r)
        Pp[((size_t)(row + r) << 8) + col] = acc[rt][ct][r];
    }
}

// ---------------------------------------------------------------------------
// K4: h = dis[i]*(sum_sp P + Yrm[i]); out = h @ Wb^T + b
// 16 rows x 256 cols per block, 4 waves; Wbf frag-ordered (coalesced)
// ---------------------------------------------------------------------------
__global__ __launch_bounds__(256) void k_out(const float* __restrict__ P,
                                             const short* __restrict__ Yrm,
                                             const short* __restrict__ Wbf,
                                             const float* __restrict__ dis,
                                             const float* __restrict__ bias,
                                             float* __restrict__ out,
                                             int splits) {
  const int w = threadIdx.x >> 6, l = threadIdx.x & 63, lr = l & 15, lq = l >> 4;
  const int row0 = (int)blockIdx.x << 4;
  const int col0 = w << 6;
  const int row = row0 + lr;
  const float di = dis[row];

  const short* Ww = Wbf + ((size_t)w << 14) + (l << 3);

  f32x4 acc[4];
#pragma unroll
  for (int ct = 0; ct < 4; ++ct) acc[ct] = (f32x4){0.f, 0.f, 0.f, 0.f};

  for (int s = 0; s < 8; ++s) {
    const int f0 = (s << 5) + (lq << 3);
    s16x8 wf[4];
#pragma unroll
    for (int ct = 0; ct < 4; ++ct)
      wf[ct] = *(const s16x8*)(Ww + (ct << 12) + (s << 9));

    const float* p = P + ((size_t)row << 8) + f0;
    f32x4 u0 = *(const f32x4*)(p);
    f32x4 u1 = *(const f32x4*)(p + 4);
#pragma unroll 3
    for (int sp = 1; sp < splits; ++sp) {
      const float* q = p + ((size_t)sp << 21);
      u0 += *(const f32x4*)(q);
      u1 += *(const f32x4*)(q + 4);
    }
    s16x8 y = *(const s16x8*)(Yrm + ((size_t)row << 8) + f0);
    i32x4 t;
    t.x = (int)pkbf((u0.x + bf2f(y[0])) * di, (u0.y + bf2f(y[1])) * di);
    t.y = (int)pkbf((u0.z + bf2f(y[2])) * di, (u0.w + bf2f(y[3])) * di);
    t.z = (int)pkbf((u1.x + bf2f(y[4])) * di, (u1.y + bf2f(y[5])) * di);
    t.w = (int)pkbf((u1.z + bf2f(y[6])) * di, (u1.w + bf2f(y[7])) * di);
    const s16x8 af = __builtin_bit_cast(s16x8, t);
#pragma unroll
    for (int ct = 0; ct < 4; ++ct)
      acc[ct] = __builtin_amdgcn_mfma_f32_16x16x32_bf16(af, wf[ct], acc[ct],
                                                        0, 0, 0);
  }

#pragma unroll
  for (int ct = 0; ct < 4; ++ct) {
    const int col = col0 + (ct << 4) + lr;
    const float bb = bias[col];
#pragma unroll
    for (int r = 0; r < 4; ++r)
      out[((size_t)(row0 + (lq << 2) + r) << 8) + col] = acc[ct][r] + bb;
  }
}

// ---------------------------------------------------------------------------
extern "C" void kernel_launch(void* const* d_in, const int* in_sizes, int n_in,
                              void* d_out, int out_size, void* d_ws,
                              size_t ws_size, hipStream_t stream) {
  const float* X = (const float*)d_in[0];
  const float* A = (const float*)d_in[1];
  const float* W = (const float*)d_in[2];
  const float* b = (const float*)d_in[3];
  float* out = (float*)d_out;

  char* ws = (char*)d_ws;
  float* dis = (float*)ws;                          // 32 KB
  short* Ytf = (short*)(ws + 32768);                // 4 MB (frag-ordered)
  short* Yrm = (short*)(ws + 32768 + 4194304);      // 4 MB
  short* Wbf = (short*)(ws + 32768 + 2 * 4194304);  // 128 KB (frag-ordered)
  const size_t base = 32768 + 2ull * 4194304 + 131072;
  short* Abf = (short*)(ws + base);                 // 128 MB bf16(A)
  const size_t pbase = base + 2ull * NROW * NCOL;
  float* P = (float*)(ws + pbase);                  // splits * 8 MB

  const int splits = (ws_size >= pbase + 4ull * 8388608) ? 4 : 2;

  k_deg<<<2048, 256, 0, stream>>>(A, dis, Abf);
  k_prep<<<160, 256, 0, stream>>>(X, W, dis, Ytf, Yrm, Wbf);
  k_gemm<<<dim3(64, splits), 512, 0, stream>>>(Abf, Ytf, P, splits);
  k_out<<<512, 256, 0, stream>>>(P, Yrm, Wbf, dis, b, out, splits);
}

// Round 7
// 452.855 us; speedup vs baseline: 1.0310x; 1.0310x over previous
//
#include <hip/hip_runtime.h>
#include <hip/hip_bf16.h>
#include <stdint.h>

#define NROW 8192
#define NCOL 8192
#define INF 256
#define OUTF 256

typedef __attribute__((ext_vector_type(4))) float f32x4;
typedef __attribute__((ext_vector_type(8))) short s16x8;
typedef __attribute__((ext_vector_type(4))) int i32x4;
typedef __attribute__((ext_vector_type(2))) unsigned int u32x2;

__device__ __forceinline__ short f2bf(float f) {
  unsigned int u = __builtin_bit_cast(unsigned int, f);
  unsigned int r = (u + 0x7FFFu + ((u >> 16) & 1u)) >> 16;  // RTNE
  return (short)r;
}
__device__ __forceinline__ float bf2f(short s) {
  unsigned int u = ((unsigned int)(unsigned short)s) << 16;
  return __builtin_bit_cast(float, u);
}
__device__ __forceinline__ unsigned int pkbf(float lo, float hi) {
#if __has_builtin(__builtin_amdgcn_cvt_pk_bf16_f32)
  auto t = __builtin_amdgcn_cvt_pk_bf16_f32(lo, hi);
  return __builtin_bit_cast(unsigned int, t);
#else
  unsigned int r;
  asm("v_cvt_pk_bf16_f32 %0, %1, %2" : "=v"(r) : "v"(lo), "v"(hi));
  return r;
#endif
}

#define GLDS(g, l)                                                            \
  __builtin_amdgcn_global_load_lds(                                           \
      (const __attribute__((address_space(1))) void*)(g),                     \
      (__attribute__((address_space(3))) void*)(l), 16, 0, 0)

// ---------------------------------------------------------------------------
// K1: dis[i] = 1/sqrt(1 + sum_j A[i,j]); one wave per row, 4 rows/block
// ---------------------------------------------------------------------------
__global__ __launch_bounds__(256) void k_deg(const float* __restrict__ A,
                                             float* __restrict__ dis) {
  const int wave = threadIdx.x >> 6, lane = threadIdx.x & 63;
  const int row = (blockIdx.x << 2) + wave;
  const f32x4* Ar = (const f32x4*)(A + (size_t)row * NCOL);
  float s = 0.f;
#pragma unroll 8
  for (int it = 0; it < 32; ++it) {
    f32x4 v = Ar[(it << 6) + lane];
    s += (v.x + v.y) + (v.z + v.w);
  }
#pragma unroll
  for (int off = 32; off > 0; off >>= 1) s += __shfl_down(s, off, 64);
  if (lane == 0) dis[row] = 1.0f / sqrtf(s + 1.0f);
}

// ---------------------------------------------------------------------------
// K2: Z = d ⊙ (X @ W^T)  [8192 x 256], bf16 MFMA, fp32 acc.
// Associativity: out = Anorm@(X@W^T)+b, so the 256x256 W-GEMM happens ONCE
// here instead of inside the big-N epilogue.
// Outputs: Ztf (MFMA-B fragment order, feeds k_gemm) and Zrm (row-major,
// for the +I term in k_fin).
// Block: 32 j-rows x 256 o-cols, 4 waves (wave w = o-strip of 64).
// ---------------------------------------------------------------------------
__global__ __launch_bounds__(256) void k_z(const float* __restrict__ X,
                                           const float* __restrict__ W,
                                           const float* __restrict__ dis,
                                           short* __restrict__ Ztf,
                                           short* __restrict__ Zrm) {
  __shared__ float sd[32];
  const int tid = threadIdx.x;
  const int w = tid >> 6, l = tid & 63, lr = l & 15, lq = l >> 4;
  const int jb = (int)blockIdx.x << 5;
  if (tid < 32) sd[tid] = dis[jb + tid];
  __syncthreads();

  f32x4 acc[2][4];
#pragma unroll
  for (int rt = 0; rt < 2; ++rt)
#pragma unroll
    for (int ct = 0; ct < 4; ++ct) acc[rt][ct] = (f32x4){0.f, 0.f, 0.f, 0.f};

  for (int s = 0; s < 8; ++s) {
    const int f0 = (s << 5) + (lq << 3);
    s16x8 bf[4];
#pragma unroll
    for (int ct = 0; ct < 4; ++ct) {  // B-frag: n = o, k = f
      const float* wp = W + (size_t)((w << 6) + (ct << 4) + lr) * INF + f0;
      f32x4 u0 = *(const f32x4*)(wp);
      f32x4 u1 = *(const f32x4*)(wp + 4);
      i32x4 t;
      t.x = (int)pkbf(u0.x, u0.y); t.y = (int)pkbf(u0.z, u0.w);
      t.z = (int)pkbf(u1.x, u1.y); t.w = (int)pkbf(u1.z, u1.w);
      bf[ct] = __builtin_bit_cast(s16x8, t);
    }
#pragma unroll
    for (int rt = 0; rt < 2; ++rt) {  // A-frag: m = j, k = f, scaled by d_j
      const int jl = (rt << 4) + lr;
      const float* xp = X + (size_t)(jb + jl) * INF + f0;
      const float d = sd[jl];
      f32x4 u0 = *(const f32x4*)(xp);
      f32x4 u1 = *(const f32x4*)(xp + 4);
      i32x4 t;
      t.x = (int)pkbf(u0.x * d, u0.y * d); t.y = (int)pkbf(u0.z * d, u0.w * d);
      t.z = (int)pkbf(u1.x * d, u1.y * d); t.w = (int)pkbf(u1.z * d, u1.w * d);
      const s16x8 af = __builtin_bit_cast(s16x8, t);
#pragma unroll
      for (int ct = 0; ct < 4; ++ct)
        acc[rt][ct] = __builtin_amdgcn_mfma_f32_16x16x32_bf16(
            af, bf[ct], acc[rt][ct], 0, 0, 0);
    }
  }

  // D-frag: lane l holds (j = jb + rt*16 + lq*4 + r, o = w*64 + ct*16 + lr)
#pragma unroll
  for (int rt = 0; rt < 2; ++rt)
#pragma unroll
    for (int ct = 0; ct < 4; ++ct) {
      const int o = (w << 6) + (ct << 4) + lr;
      // Ztf: frag(ft = o>>4 = w*4+ct, kb = j>>5 = blockIdx.x);
      // lane' = (o&15) + 16*((j&31)>>3); elem = j&7 -> 4 consecutive (lq&1)*4+r
      const int lane2 = lr + (((rt << 1) + (lq >> 1)) << 4);
      u32x2 p;
      p.x = pkbf(acc[rt][ct].x, acc[rt][ct].y);
      p.y = pkbf(acc[rt][ct].z, acc[rt][ct].w);
      const size_t dst = (((size_t)((w << 2) + ct) << 8) + blockIdx.x) * 512 +
                         (lane2 << 3) + ((lq & 1) << 2);
      *(u32x2*)(Ztf + dst) = p;
      // Zrm: row-major scatter (tiny kernel, 2-B stores)
      const int jrow = jb + (rt << 4) + (lq << 2);
#pragma unroll
      for (int r = 0; r < 4; ++r)
        Zrm[(size_t)(jrow + r) * OUTF + o] = f2bf(acc[rt][ct][r]);
    }
}

// ---------------------------------------------------------------------------
// K3: P[sp] = A[64 rows, ksp] @ Ztf^T  (bf16 MFMA, fp32 acc) — R4 geometry.
// BM=64 BN=256 BK=64; A fp32 via GLDS into 2-buffer swizzled LDS;
// B via coalesced frag-ordered loads from L2-resident Ztf.
// ---------------------------------------------------------------------------
__device__ __forceinline__ s16x8 ldcvt(const float* buf, int n, int kc, int lq) {
  const int base = (n << 6) + (kc << 5);
  const int sw = n & 7;
  f32x4 u0 = *(const f32x4*)(buf + base + ((((lq << 1) | 0) ^ sw) << 2));
  f32x4 u1 = *(const f32x4*)(buf + base + ((((lq << 1) | 1) ^ sw) << 2));
  i32x4 t;
  t.x = (int)pkbf(u0.x, u0.y);
  t.y = (int)pkbf(u0.z, u0.w);
  t.z = (int)pkbf(u1.x, u1.y);
  t.w = (int)pkbf(u1.z, u1.w);
  return __builtin_bit_cast(s16x8, t);
}

__global__ __launch_bounds__(256, 2) void k_gemm(const float* __restrict__ A,
                                                 const short* __restrict__ Ztf,
                                                 float* __restrict__ P,
                                                 int splits) {
  __shared__ float Ab[2 * 4096];  // 2 x (64 rows x 64 floats), chunk-swizzled
  const int tid = threadIdx.x;
  const int w = tid >> 6, l = tid & 63, lr = l & 15, lq = l >> 4;
  const int row0 = (int)blockIdx.x << 6;
  const int sp = blockIdx.y;
  const int kspan = NCOL / splits;
  const int k0 = sp * kspan;
  const int steps = kspan >> 6;

  const char* gA[4];
#pragma unroll
  for (int j = 0; j < 4; ++j) {
    const int p = tid + (j << 8);
    const int n = p >> 4, h = (p >> 3) & 1, cpos = p & 7;
    const int c = cpos ^ (n & 7);
    gA[j] = (const char*)(A + (size_t)(row0 + n) * NCOL + k0 + (h << 5) + (c << 2));
  }
  char* ldst0 = (char*)Ab + ((tid & ~63) << 4);

  // frag-ordered B: frag (ftile = w*4+ct, kb) at Ztf[(ftile*256+kb)*512 + l*8]
  const short* Bw = Ztf + ((size_t)w << 19) + ((size_t)(k0 >> 5) << 9) + (l << 3);

  f32x4 acc[4][4];
#pragma unroll
  for (int rt = 0; rt < 4; ++rt)
#pragma unroll
    for (int ct = 0; ct < 4; ++ct) acc[rt][ct] = (f32x4){0.f, 0.f, 0.f, 0.f};

  // prologue: DMA(0); B(0, kc=0)
#pragma unroll
  for (int j = 0; j < 4; ++j) GLDS(gA[j], ldst0 + (j << 12));
  i32x4 bB0[4];
#pragma unroll
  for (int ct = 0; ct < 4; ++ct)
    bB0[ct] = *(const i32x4*)(Bw + ((size_t)ct << 17));

  for (int s = 0; s < steps; ++s) {
    __syncthreads();  // drains DMA(s) + B-prefetches for step s

    if (s + 1 < steps) {
      char* dst = ldst0 + (((s + 1) & 1) << 14);
      const size_t go = (size_t)(s + 1) << 8;  // 256 B = 64 floats
#pragma unroll
      for (int j = 0; j < 4; ++j) GLDS(gA[j] + go, dst + (j << 12));
    }

    // B(s, kc=1), coalesced
    i32x4 bB1[4];
#pragma unroll
    for (int ct = 0; ct < 4; ++ct)
      bB1[ct] = *(const i32x4*)(Bw + ((size_t)ct << 17) +
                                ((size_t)((s << 1) + 1) << 9));

    const float* buf = Ab + ((s & 1) << 12);

    // ---- kc = 0 ----
    s16x8 af[4];
#pragma unroll
    for (int rt = 0; rt < 4; ++rt) af[rt] = ldcvt(buf, (rt << 4) + lr, 0, lq);
#pragma unroll
    for (int rt = 0; rt < 4; ++rt) {
      const s16x8 a = af[rt];
#pragma unroll
      for (int ct = 0; ct < 4; ++ct)
        acc[rt][ct] = __builtin_amdgcn_mfma_f32_16x16x32_bf16(
            a, __builtin_bit_cast(s16x8, bB0[ct]), acc[rt][ct], 0, 0, 0);
    }

    if (s + 1 < steps) {  // prefetch B(s+1, kc=0)
#pragma unroll
      for (int ct = 0; ct < 4; ++ct)
        bB0[ct] = *(const i32x4*)(Bw + ((size_t)ct << 17) +
                                  ((size_t)((s << 1) + 2) << 9));
    }

    // ---- kc = 1 ----
#pragma unroll
    for (int rt = 0; rt < 4; ++rt) af[rt] = ldcvt(buf, (rt << 4) + lr, 1, lq);
#pragma unroll
    for (int rt = 0; rt < 4; ++rt) {
      const s16x8 a = af[rt];
#pragma unroll
      for (int ct = 0; ct < 4; ++ct)
        acc[rt][ct] = __builtin_amdgcn_mfma_f32_16x16x32_bf16(
            a, __builtin_bit_cast(s16x8, bB1[ct]), acc[rt][ct], 0, 0, 0);
    }
  }

  float* Pp = P + ((size_t)sp << 21);
#pragma unroll
  for (int rt = 0; rt < 4; ++rt)
#pragma unroll
    for (int ct = 0; ct < 4; ++ct) {
      const int col = (w << 6) + (ct << 4) + lr;
      const int row = row0 + (rt << 4) + (lq << 2);
#pragma unroll
      for (int r = 0; r < 4; ++r)
        Pp[((size_t)(row + r) << 8) + col] = acc[rt][ct][r];
    }
}

// ---------------------------------------------------------------------------
// K4: out[i,o] = dis[i]*(sum_sp P + Z[i,o]) + b[o]  — pure coalesced reduce.
// One f32x4 per thread; a wave covers exactly one row (dis wave-uniform).
// ---------------------------------------------------------------------------
__global__ __launch_bounds__(256) void k_fin(const float* __restrict__ P,
                                             const short* __restrict__ Zrm,
                                             const float* __restrict__ dis,
                                             const float* __restrict__ bias,
                                             float* __restrict__ out,
                                             int splits) {
  const int q = (int)blockIdx.x * 256 + threadIdx.x;
  const int i = q >> 6;
  const int o0 = (q & 63) << 2;
  const float di = dis[i];
  const float* p = P + ((size_t)i << 8) + o0;
  f32x4 u = *(const f32x4*)p;
#pragma unroll 3
  for (int sp = 1; sp < 4; ++sp) u += *(const f32x4*)(p + ((size_t)sp << 21));
  u32x2 zz = *(const u32x2*)(Zrm + ((size_t)i << 8) + o0);
  f32x4 z;
  z.x = bf2f((short)(zz.x & 0xFFFF));
  z.y = bf2f((short)(zz.x >> 16));
  z.z = bf2f((short)(zz.y & 0xFFFF));
  z.w = bf2f((short)(zz.y >> 16));
  f32x4 bb = *(const f32x4*)(bias + o0);
  f32x4 r = (u + z) * di + bb;
  *(f32x4*)(out + ((size_t)i << 8) + o0) = r;
}

// ---------------------------------------------------------------------------
extern "C" void kernel_launch(void* const* d_in, const int* in_sizes, int n_in,
                              void* d_out, int out_size, void* d_ws,
                              size_t ws_size, hipStream_t stream) {
  const float* X = (const float*)d_in[0];
  const float* A = (const float*)d_in[1];
  const float* W = (const float*)d_in[2];
  const float* b = (const float*)d_in[3];
  float* out = (float*)d_out;

  char* ws = (char*)d_ws;
  float* dis = (float*)ws;                       // 32 KB
  short* Ztf = (short*)(ws + 32768);             // 4 MB (frag-ordered Z)
  short* Zrm = (short*)(ws + 32768 + 4194304);   // 4 MB (row-major Z)
  float* P = (float*)(ws + 32768 + 2 * 4194304); // 4 x 8 MB split-K partials

  k_deg<<<2048, 256, 0, stream>>>(A, dis);
  k_z<<<256, 256, 0, stream>>>(X, W, dis, Ztf, Zrm);
  k_gemm<<<dim3(128, 4), 256, 0, stream>>>(A, Ztf, P, 4);
  k_fin<<<2048, 256, 0, stream>>>(P, Zrm, dis, b, out, 4);
}